// Round 2
// baseline (11109.998 us; speedup 1.0000x reference)
//
#include <hip/hip_runtime.h>
#include <hip/hip_bf16.h>
#include <math.h>
#include <stddef.h>

#define S_LEN 512
#define NBATCH 64
#define HID 1024
#define IN_SZ 1024
#define KTOT 2048        // rows of W: 0..1023 = h, 1024..2047 = x
#define NB 128           // recurrent blocks
#define NCOLS 32         // 4 gates x 8 hidden per block
#define JPB 8

using short8  = __attribute__((ext_vector_type(8))) short;
using floatx4 = __attribute__((ext_vector_type(4))) float;

// ---- workspace layout (bytes) ----
// Wpack : [NB][NCOLS][KTOT] bf16   = 16,777,216
// x_bf  : [B][S][IN] bf16          = 67,108,864
// h_buf : [S+1][B][HID] bf16       = 67,239,936
// flags : int[128]
static const size_t WPACK_OFF = 0;
static const size_t XBF_OFF   = 16777216;
static const size_t HBUF_OFF  = XBF_OFF + 67108864;     // 83,886,080
static const size_t FLAGS_OFF = HBUF_OFF + 67239936;    // 151,126,016

__device__ __forceinline__ unsigned short f2b(float f) {
  __hip_bfloat16 h = __float2bfloat16(f);
  return *reinterpret_cast<unsigned short*>(&h);
}
__device__ __forceinline__ float sigm(float z) {
  z = fminf(fmaxf(z, -30.f), 30.f);
  return 1.f / (1.f + __expf(-z));
}
__device__ __forceinline__ float tanh_(float z) {
  z = fminf(fmaxf(z, -15.f), 15.f);
  float e = __expf(2.f * z);
  return (e - 1.f) / (e + 1.f);
}

// ---- prep: transpose W (2048x1024 fp32, k-major rows) -> Wpack[p][c][k] bf16 ----
__global__ void prep_w(const float* __restrict__ Wf, const float* __restrict__ Wi,
                       const float* __restrict__ Wc, const float* __restrict__ Wo,
                       __hip_bfloat16* __restrict__ wpack) {
  __shared__ float tile[64][65];
  const int g = blockIdx.z;
  const float* W = (g == 0) ? Wf : (g == 1) ? Wi : (g == 2) ? Wc : Wo;
  const int k0 = blockIdx.x * 64, j0 = blockIdx.y * 64;
  const int tx = threadIdx.x, ty = threadIdx.y;
  for (int kk = 0; kk < 64; kk += 4)
    tile[kk + ty][tx] = W[(size_t)(k0 + kk + ty) * HID + j0 + tx];
  __syncthreads();
  for (int jj = 0; jj < 64; jj += 4) {
    int j = j0 + jj + ty;
    size_t out = ((size_t)((j >> 3) * NCOLS + g * 8 + (j & 7))) * KTOT + k0 + tx;
    wpack[out] = __float2bfloat16(tile[tx][jj + ty]);
  }
}

// ---- prep: x -> bf16, zero flags ----
__global__ void prep_x(const float* __restrict__ x, unsigned short* __restrict__ xbf,
                       int* __restrict__ flags) {
  size_t i = ((size_t)blockIdx.x * blockDim.x + threadIdx.x) * 4;
  float4 v = *(const float4*)(x + i);
  ushort4 u;
  u.x = f2b(v.x); u.y = f2b(v.y); u.z = f2b(v.z); u.w = f2b(v.w);
  *(ushort4*)(xbf + i) = u;
  if (blockIdx.x == 0 && threadIdx.x < NB) flags[threadIdx.x] = 0;
}

// ---- persistent recurrent kernel (regular launch; 128 blocks on 256 CUs
// are trivially co-resident, sync is via flags not grid.sync) ----
__launch_bounds__(256, 1)
__global__ void lstm_rec(const unsigned short* __restrict__ xbf,
                         const unsigned short* __restrict__ wpack,
                         const float* __restrict__ bfv, const float* __restrict__ biv,
                         const float* __restrict__ bcv, const float* __restrict__ bov,
                         unsigned short* __restrict__ hbuf,
                         int* __restrict__ flags,
                         float* __restrict__ out) {
  __shared__ float part[4][64][36];   // [wave][lane][m*8+n*4+r], stride 36 for banking
  const int tid  = threadIdx.x;
  const int w    = tid >> 6;          // wave 0..3 ; 0,1 = h-half of K, 2,3 = x-half
  const int lane = tid & 63;
  const int l15  = lane & 15;
  const int lq   = lane >> 4;
  const int p    = blockIdx.x;
  const int j0   = p * JPB;

  // B-operand: this wave's k-quarter of the block's W slice, resident in VGPRs.
  short8 Wreg[32];
  {
    const unsigned short* wp = wpack + (size_t)p * NCOLS * KTOT;
#pragma unroll
    for (int ks = 0; ks < 16; ++ks)
#pragma unroll
      for (int n = 0; n < 2; ++n) {
        int c = n * 16 + l15;
        int k = w * 512 + ks * 32 + lq * 8;
        Wreg[ks * 2 + n] = *(const short8*)(wp + (size_t)c * KTOT + k);
      }
  }
  float bias0, bias1;
  {
    int c = l15;
    bias0 = (c < 8) ? bfv[j0 + c] : biv[j0 + c - 8];
    bias1 = (c < 8) ? bcv[j0 + c] : bov[j0 + c - 8];
  }
  float Cst[4]  = {0.f, 0.f, 0.f, 0.f};
  float hmax[4] = {-__builtin_inff(), -__builtin_inff(), -__builtin_inff(), -__builtin_inff()};
  const int  jj    = l15 & 7;
  const bool act   = (l15 < 8);
  const int  bbase = w * 16 + lq * 4;       // epilogue: wave owns Mtile w
  const bool is_x  = (w >= 2);

  for (int t = 0; t < S_LEN; ++t) {
    floatx4 acc[4][2];
#pragma unroll
    for (int m = 0; m < 4; ++m) { acc[m][0] = (floatx4){0,0,0,0}; acc[m][1] = (floatx4){0,0,0,0}; }

    if (is_x) {
      // x-half of K: no dependency, runs before the sync point
      const unsigned short* xa = xbf + (size_t)t * IN_SZ + (w - 2) * 512 + lq * 8;
#pragma unroll
      for (int ks = 0; ks < 16; ++ks) {
        short8 a[4];
#pragma unroll
        for (int m = 0; m < 4; ++m)
          a[m] = *(const short8*)(xa + (size_t)(m * 16 + l15) * ((size_t)S_LEN * IN_SZ) + ks * 32);
#pragma unroll
        for (int m = 0; m < 4; ++m) {
          acc[m][0] = __builtin_amdgcn_mfma_f32_16x16x32_bf16(a[m], Wreg[ks * 2 + 0], acc[m][0], 0, 0, 0);
          acc[m][1] = __builtin_amdgcn_mfma_f32_16x16x32_bf16(a[m], Wreg[ks * 2 + 1], acc[m][1], 0, 0, 0);
        }
      }
    } else if (t > 0) {
      // wait until every block has published h_buf[t]
      {
        bool ready;
        do {
          int a = __hip_atomic_load(&flags[lane],      __ATOMIC_ACQUIRE, __HIP_MEMORY_SCOPE_AGENT);
          int b = __hip_atomic_load(&flags[lane + 64], __ATOMIC_ACQUIRE, __HIP_MEMORY_SCOPE_AGENT);
          ready = __all((a >= t) && (b >= t));
        } while (!ready);
      }
      const unsigned short* ha = hbuf + (size_t)t * (NBATCH * HID) + w * 512 + lq * 8;
#pragma unroll
      for (int ks = 0; ks < 16; ++ks) {
        short8 a[4];
#pragma unroll
        for (int m = 0; m < 4; ++m)
          a[m] = *(const short8*)(ha + (size_t)(m * 16 + l15) * HID + ks * 32);
#pragma unroll
        for (int m = 0; m < 4; ++m) {
          acc[m][0] = __builtin_amdgcn_mfma_f32_16x16x32_bf16(a[m], Wreg[ks * 2 + 0], acc[m][0], 0, 0, 0);
          acc[m][1] = __builtin_amdgcn_mfma_f32_16x16x32_bf16(a[m], Wreg[ks * 2 + 1], acc[m][1], 0, 0, 0);
        }
      }
    }
    // publish partials
#pragma unroll
    for (int m = 0; m < 4; ++m) {
      *(floatx4*)&part[w][lane][m * 8 + 0] = acc[m][0];
      *(floatx4*)&part[w][lane][m * 8 + 4] = acc[m][1];
    }
    __syncthreads();
    // reduce my Mtile (=w) across the 4 k-quarters
    floatx4 r0 = {0, 0, 0, 0}, r1 = {0, 0, 0, 0};
#pragma unroll
    for (int sw = 0; sw < 4; ++sw) {
      r0 += *(const floatx4*)&part[sw][lane][w * 8 + 0];
      r1 += *(const floatx4*)&part[sw][lane][w * 8 + 4];
    }
    // epilogue: C/D layout col=l15, row=lq*4+r. cols 0..7=f,8..15=i | 16..23=c,24..31=o
#pragma unroll
    for (int r = 0; r < 4; ++r) {
      float g0  = r0[r] + bias0;
      float g1  = r1[r] + bias1;
      float g0o = __shfl_xor(g0, 8);
      float g1o = __shfl_xor(g1, 8);
      float fg = sigm(g0);        // valid on lanes l15<8
      float ig = sigm(g0o);
      float cg = tanh_(g1);
      float og = sigm(g1o);
      float C  = fg * Cst[r] + ig * cg;
      Cst[r] = C;
      float h = og * tanh_(C);
      int b = bbase + r;
      if (act)
        out[(size_t)b * ((size_t)S_LEN * HID) + (size_t)t * HID + j0 + jj] = h;
      float hm = fmaxf(hmax[r], h);
      hmax[r] = hm;
      // publish running max as next-step hidden (bf16 pairs, device-visible stores)
      unsigned int hb    = f2b(hm);
      unsigned int other = (unsigned int)__shfl_xor((int)hb, 1) & 0xffffu;
      if (act && ((jj & 1) == 0)) {
        unsigned int word = hb | (other << 16);
        unsigned int* dst = (unsigned int*)(hbuf + (size_t)(t + 1) * (NBATCH * HID) + (size_t)b * HID + j0 + jj);
        __hip_atomic_store(dst, word, __ATOMIC_RELAXED, __HIP_MEMORY_SCOPE_AGENT);
      }
    }
    __syncthreads();   // drains all waves' vmcnt -> h_buf[t+1] globally visible
    if (tid == 0)
      __hip_atomic_store(&flags[p], t + 1, __ATOMIC_RELEASE, __HIP_MEMORY_SCOPE_AGENT);
  }
  // finals: h_fin = running max, C_fin
  const size_t HSEQ = (size_t)NBATCH * S_LEN * HID;
#pragma unroll
  for (int r = 0; r < 4; ++r) {
    int b = bbase + r;
    if (act) {
      out[HSEQ + (size_t)b * HID + j0 + jj] = hmax[r];
      out[HSEQ + (size_t)NBATCH * HID + (size_t)b * HID + j0 + jj] = Cst[r];
    }
  }
}

extern "C" void kernel_launch(void* const* d_in, const int* in_sizes, int n_in,
                              void* d_out, int out_size, void* d_ws, size_t ws_size,
                              hipStream_t stream) {
  const float* x   = (const float*)d_in[0];
  const float* Wf  = (const float*)d_in[1];
  const float* bf_ = (const float*)d_in[2];
  const float* Wi  = (const float*)d_in[3];
  const float* bi_ = (const float*)d_in[4];
  const float* Wc  = (const float*)d_in[5];
  const float* bc_ = (const float*)d_in[6];
  const float* Wo  = (const float*)d_in[7];
  const float* bo_ = (const float*)d_in[8];
  char* ws = (char*)d_ws;
  __hip_bfloat16* wpack_bf = (__hip_bfloat16*)(ws + WPACK_OFF);
  unsigned short* xbf      = (unsigned short*)(ws + XBF_OFF);
  unsigned short* hbuf     = (unsigned short*)(ws + HBUF_OFF);
  int* flags               = (int*)(ws + FLAGS_OFF);
  float* outp              = (float*)d_out;

  hipLaunchKernelGGL(prep_w, dim3(KTOT / 64, HID / 64, 4), dim3(64, 4, 1), 0, stream,
                     Wf, Wi, Wc, Wo, wpack_bf);
  hipLaunchKernelGGL(prep_x, dim3(32768), dim3(256), 0, stream, x, xbf, flags);

  lstm_rec<<<dim3(NB), dim3(256), 0, stream>>>(
      xbf, (const unsigned short*)wpack_bf, bf_, bi_, bc_, bo_, hbuf, flags, outp);
}

// Round 3
// 6899.726 us; speedup vs baseline: 1.6102x; 1.6102x over previous
//
#include <hip/hip_runtime.h>
#include <hip/hip_bf16.h>
#include <math.h>
#include <stddef.h>

#define S_LEN 512
#define NBATCH 64
#define HID 1024
#define IN_SZ 1024
#define KTOT 2048        // rows of W: 0..1023 = h, 1024..2047 = x
#define NB 128           // recurrent blocks
#define NCOLS 32         // 4 gates x 8 hidden per block
#define JPB 8

using short8  = __attribute__((ext_vector_type(8))) short;
using floatx4 = __attribute__((ext_vector_type(4))) float;

// ---- workspace layout (bytes) ----
static const size_t WPACK_OFF = 0;
static const size_t XBF_OFF   = 16777216;
static const size_t HBUF_OFF  = XBF_OFF + 67108864;     // 83,886,080
static const size_t FLAGS_OFF = HBUF_OFF + 67239936;    // 151,126,016

__device__ __forceinline__ unsigned short f2b(float f) {
  __hip_bfloat16 h = __float2bfloat16(f);
  return *reinterpret_cast<unsigned short*>(&h);
}
__device__ __forceinline__ float sigm(float z) {
  z = fminf(fmaxf(z, -30.f), 30.f);
  return 1.f / (1.f + __expf(-z));
}
__device__ __forceinline__ float tanh_(float z) {
  z = fminf(fmaxf(z, -15.f), 15.f);
  float e = __expf(2.f * z);
  return (e - 1.f) / (e + 1.f);
}

// ---- prep: transpose W (2048x1024 fp32, k-major rows) -> Wpack[p][c][k] bf16 ----
__global__ void prep_w(const float* __restrict__ Wf, const float* __restrict__ Wi,
                       const float* __restrict__ Wc, const float* __restrict__ Wo,
                       __hip_bfloat16* __restrict__ wpack) {
  __shared__ float tile[64][65];
  const int g = blockIdx.z;
  const float* W = (g == 0) ? Wf : (g == 1) ? Wi : (g == 2) ? Wc : Wo;
  const int k0 = blockIdx.x * 64, j0 = blockIdx.y * 64;
  const int tx = threadIdx.x, ty = threadIdx.y;
  for (int kk = 0; kk < 64; kk += 4)
    tile[kk + ty][tx] = W[(size_t)(k0 + kk + ty) * HID + j0 + tx];
  __syncthreads();
  for (int jj = 0; jj < 64; jj += 4) {
    int j = j0 + jj + ty;
    size_t out = ((size_t)((j >> 3) * NCOLS + g * 8 + (j & 7))) * KTOT + k0 + tx;
    wpack[out] = __float2bfloat16(tile[tx][jj + ty]);
  }
}

// ---- prep: x -> bf16, zero flags ----
__global__ void prep_x(const float* __restrict__ x, unsigned short* __restrict__ xbf,
                       int* __restrict__ flags) {
  size_t i = ((size_t)blockIdx.x * blockDim.x + threadIdx.x) * 4;
  float4 v = *(const float4*)(x + i);
  ushort4 u;
  u.x = f2b(v.x); u.y = f2b(v.y); u.z = f2b(v.z); u.w = f2b(v.w);
  *(ushort4*)(xbf + i) = u;
  if (blockIdx.x == 0 && threadIdx.x < NB) flags[threadIdx.x] = 0;
}

// ---- persistent recurrent kernel ----
// Sync protocol (all relaxed, no acquire/release cache-maintenance in the loop):
//  * h stores are agent-scope relaxed atomics -> sc1 write-through to LLC,
//    never dirty in local L2.
//  * __syncthreads() drains vmcnt(0) per wave -> sc1 stores acked at LLC.
//  * flag store relaxed agent (sc1) AFTER the barrier -> readers seeing
//    flag>=t+1 are guaranteed the h data is at the LLC.
//  * reader h addresses are fresh each step (never touched by this XCD) ->
//    plain cached loads must miss L1/L2 and fetch the LLC copy.
//  (Round-2 used acquire polls + release flag stores: the implied
//   buffer_inv / buffer_wbl2 L2 walks cost ~21 us/step.)
__launch_bounds__(256, 1)
__global__ void lstm_rec(const unsigned short* __restrict__ xbf,
                         const unsigned short* __restrict__ wpack,
                         const float* __restrict__ bfv, const float* __restrict__ biv,
                         const float* __restrict__ bcv, const float* __restrict__ bov,
                         unsigned short* __restrict__ hbuf,
                         int* __restrict__ flags,
                         float* __restrict__ out) {
  __shared__ float part[4][64][36];   // [wave][lane][m*8+n*4+r], stride 36 for banking
  const int tid  = threadIdx.x;
  const int w    = tid >> 6;          // wave 0..3 ; 0,1 = h-half of K, 2,3 = x-half
  const int lane = tid & 63;
  const int l15  = lane & 15;
  const int lq   = lane >> 4;
  const int p    = blockIdx.x;
  const int j0   = p * JPB;

  // B-operand: this wave's k-quarter of the block's W slice, resident in VGPRs.
  short8 Wreg[32];
  {
    const unsigned short* wp = wpack + (size_t)p * NCOLS * KTOT;
#pragma unroll
    for (int ks = 0; ks < 16; ++ks)
#pragma unroll
      for (int n = 0; n < 2; ++n) {
        int c = n * 16 + l15;
        int k = w * 512 + ks * 32 + lq * 8;
        Wreg[ks * 2 + n] = *(const short8*)(wp + (size_t)c * KTOT + k);
      }
  }
  float bias0, bias1;
  {
    int c = l15;
    bias0 = (c < 8) ? bfv[j0 + c] : biv[j0 + c - 8];
    bias1 = (c < 8) ? bcv[j0 + c] : bov[j0 + c - 8];
  }
  float Cst[4]  = {0.f, 0.f, 0.f, 0.f};
  float hmax[4] = {-__builtin_inff(), -__builtin_inff(), -__builtin_inff(), -__builtin_inff()};
  const int  jj    = l15 & 7;
  const bool act   = (l15 < 8);
  const int  bbase = w * 16 + lq * 4;       // epilogue: wave owns Mtile w
  const bool is_x  = (w >= 2);

  for (int t = 0; t < S_LEN; ++t) {
    floatx4 acc[4][2];
#pragma unroll
    for (int m = 0; m < 4; ++m) { acc[m][0] = (floatx4){0,0,0,0}; acc[m][1] = (floatx4){0,0,0,0}; }

    if (is_x) {
      // x-half of K: no dependency, runs before the sync point
      const unsigned short* xa = xbf + (size_t)t * IN_SZ + (w - 2) * 512 + lq * 8;
#pragma unroll
      for (int ks = 0; ks < 16; ++ks) {
        short8 a[4];
#pragma unroll
        for (int m = 0; m < 4; ++m)
          a[m] = *(const short8*)(xa + (size_t)(m * 16 + l15) * ((size_t)S_LEN * IN_SZ) + ks * 32);
#pragma unroll
        for (int m = 0; m < 4; ++m) {
          acc[m][0] = __builtin_amdgcn_mfma_f32_16x16x32_bf16(a[m], Wreg[ks * 2 + 0], acc[m][0], 0, 0, 0);
          acc[m][1] = __builtin_amdgcn_mfma_f32_16x16x32_bf16(a[m], Wreg[ks * 2 + 1], acc[m][1], 0, 0, 0);
        }
      }
    } else if (t > 0) {
      // wait until every block has published h_buf[t] (relaxed polls: no
      // buffer_inv; flag+data both live at the LLC via sc1)
      {
        bool ready;
        do {
          int a = __hip_atomic_load(&flags[lane],      __ATOMIC_RELAXED, __HIP_MEMORY_SCOPE_AGENT);
          int b = __hip_atomic_load(&flags[lane + 64], __ATOMIC_RELAXED, __HIP_MEMORY_SCOPE_AGENT);
          ready = __all((a >= t) && (b >= t));
        } while (!ready);
        __atomic_signal_fence(__ATOMIC_ACQUIRE);   // compiler-only: no hoisting h loads
      }
      const unsigned short* ha = hbuf + (size_t)t * (NBATCH * HID) + w * 512 + lq * 8;
#pragma unroll
      for (int ks = 0; ks < 16; ++ks) {
        short8 a[4];
#pragma unroll
        for (int m = 0; m < 4; ++m)
          a[m] = *(const short8*)(ha + (size_t)(m * 16 + l15) * HID + ks * 32);
#pragma unroll
        for (int m = 0; m < 4; ++m) {
          acc[m][0] = __builtin_amdgcn_mfma_f32_16x16x32_bf16(a[m], Wreg[ks * 2 + 0], acc[m][0], 0, 0, 0);
          acc[m][1] = __builtin_amdgcn_mfma_f32_16x16x32_bf16(a[m], Wreg[ks * 2 + 1], acc[m][1], 0, 0, 0);
        }
      }
    }
    // publish partials
#pragma unroll
    for (int m = 0; m < 4; ++m) {
      *(floatx4*)&part[w][lane][m * 8 + 0] = acc[m][0];
      *(floatx4*)&part[w][lane][m * 8 + 4] = acc[m][1];
    }
    __syncthreads();
    // reduce my Mtile (=w) across the 4 k-quarters
    floatx4 r0 = {0, 0, 0, 0}, r1 = {0, 0, 0, 0};
#pragma unroll
    for (int sw = 0; sw < 4; ++sw) {
      r0 += *(const floatx4*)&part[sw][lane][w * 8 + 0];
      r1 += *(const floatx4*)&part[sw][lane][w * 8 + 4];
    }
    // epilogue: C/D layout col=l15, row=lq*4+r. cols 0..7=f,8..15=i | 16..23=c,24..31=o
#pragma unroll
    for (int r = 0; r < 4; ++r) {
      float g0  = r0[r] + bias0;
      float g1  = r1[r] + bias1;
      float g0o = __shfl_xor(g0, 8);
      float g1o = __shfl_xor(g1, 8);
      float fg = sigm(g0);        // valid on lanes l15<8
      float ig = sigm(g0o);
      float cg = tanh_(g1);
      float og = sigm(g1o);
      float C  = fg * Cst[r] + ig * cg;
      Cst[r] = C;
      float h = og * tanh_(C);
      int b = bbase + r;
      if (act)
        out[(size_t)b * ((size_t)S_LEN * HID) + (size_t)t * HID + j0 + jj] = h;
      float hm = fmaxf(hmax[r], h);
      hmax[r] = hm;
      // publish running max as next-step hidden (bf16 pairs, sc1 stores)
      unsigned int hb    = f2b(hm);
      unsigned int other = (unsigned int)__shfl_xor((int)hb, 1) & 0xffffu;
      if (act && ((jj & 1) == 0)) {
        unsigned int word = hb | (other << 16);
        unsigned int* dst = (unsigned int*)(hbuf + (size_t)(t + 1) * (NBATCH * HID) + (size_t)b * HID + j0 + jj);
        __hip_atomic_store(dst, word, __ATOMIC_RELAXED, __HIP_MEMORY_SCOPE_AGENT);
      }
    }
    __syncthreads();   // vmcnt(0) per wave -> sc1 h-stores acked at LLC
    if (tid == 0)
      __hip_atomic_store(&flags[p], t + 1, __ATOMIC_RELAXED, __HIP_MEMORY_SCOPE_AGENT);
  }
  // finals: h_fin = running max, C_fin
  const size_t HSEQ = (size_t)NBATCH * S_LEN * HID;
#pragma unroll
  for (int r = 0; r < 4; ++r) {
    int b = bbase + r;
    if (act) {
      out[HSEQ + (size_t)b * HID + j0 + jj] = hmax[r];
      out[HSEQ + (size_t)NBATCH * HID + (size_t)b * HID + j0 + jj] = Cst[r];
    }
  }
}

extern "C" void kernel_launch(void* const* d_in, const int* in_sizes, int n_in,
                              void* d_out, int out_size, void* d_ws, size_t ws_size,
                              hipStream_t stream) {
  const float* x   = (const float*)d_in[0];
  const float* Wf  = (const float*)d_in[1];
  const float* bf_ = (const float*)d_in[2];
  const float* Wi  = (const float*)d_in[3];
  const float* bi_ = (const float*)d_in[4];
  const float* Wc  = (const float*)d_in[5];
  const float* bc_ = (const float*)d_in[6];
  const float* Wo  = (const float*)d_in[7];
  const float* bo_ = (const float*)d_in[8];
  char* ws = (char*)d_ws;
  __hip_bfloat16* wpack_bf = (__hip_bfloat16*)(ws + WPACK_OFF);
  unsigned short* xbf      = (unsigned short*)(ws + XBF_OFF);
  unsigned short* hbuf     = (unsigned short*)(ws + HBUF_OFF);
  int* flags               = (int*)(ws + FLAGS_OFF);
  float* outp              = (float*)d_out;

  hipLaunchKernelGGL(prep_w, dim3(KTOT / 64, HID / 64, 4), dim3(64, 4, 1), 0, stream,
                     Wf, Wi, Wc, Wo, wpack_bf);
  hipLaunchKernelGGL(prep_x, dim3(32768), dim3(256), 0, stream, x, xbf, flags);

  lstm_rec<<<dim3(NB), dim3(256), 0, stream>>>(
      xbf, (const unsigned short*)wpack_bf, bf_, bi_, bc_, bo_, hbuf, flags, outp);
}